// Round 1
// baseline (161267.737 us; speedup 1.0000x reference)
//
#include <hip/hip_runtime.h>
#include <hip/hip_bf16.h>
#include <stdint.h>

#define T_STEPS 8192
#define NX 1024
#define NU 512
#define NY 128
#define HID 4096

#define SEQ_WGS 256
#define SEQ_BLK 512
#define COLS_PER_WG 16            // HID / SEQ_WGS
#define SEQ_LDS (COLS_PER_WG*HID*2 + HID*2)   // 131072 + 8192 = 139264

typedef __attribute__((ext_vector_type(8))) short bf16x8;
typedef __attribute__((ext_vector_type(4))) float f32x4;

__device__ __forceinline__ float bf2f(ushort u) {
  union { uint32_t i; float f; } v; v.i = ((uint32_t)u) << 16; return v.f;
}
__device__ __forceinline__ ushort f2bf(float f) {
  union { float f; uint32_t i; } v; v.f = f;
  uint32_t r = v.i + 0x7fffu + ((v.i >> 16) & 1u);
  return (ushort)(r >> 16);
}

// ---------------- small utility kernels ----------------

__global__ void init_cnt_kernel(unsigned int* cnt) {
  if (threadIdx.x == 0) cnt[0] = 0u;
}

__global__ void cvt_bf16_kernel(const float* __restrict__ in, ushort* __restrict__ out, int n) {
  int i = blockIdx.x * blockDim.x + threadIdx.x;
  int stride = gridDim.x * blockDim.x;
  for (; i < n; i += stride) out[i] = f2bf(in[i]);
}

// out[C][R] = (bf16) in[R][C]
__global__ void transpose_cvt_kernel(const float* __restrict__ in, ushort* __restrict__ out,
                                     int R, int C) {
  __shared__ float tile[32][33];
  int bx = blockIdx.x, by = blockIdx.y;
  int tx = threadIdx.x, ty = threadIdx.y;  // 32 x 8
#pragma unroll
  for (int yy = 0; yy < 4; ++yy) {
    long r = (long)by * 32 + ty + yy * 8;
    long c = (long)bx * 32 + tx;
    tile[ty + yy * 8][tx] = in[r * C + c];
  }
  __syncthreads();
#pragma unroll
  for (int yy = 0; yy < 4; ++yy) {
    long c = (long)bx * 32 + ty + yy * 8;  // out row
    long r = (long)by * 32 + tx;           // out col
    out[c * R + r] = f2bf(tile[tx][ty + yy * 8]);
  }
}

// biasDH[j] = f_b1[j] + sum_k f_b2[k] * f_w1[k][j]
__global__ void bias_dh_kernel(const float* __restrict__ fw1, const float* __restrict__ fb1,
                               const float* __restrict__ fb2, float* __restrict__ biasDH) {
  int j = blockIdx.x * blockDim.x + threadIdx.x;
  float s = fb1[j];
  for (int k = 0; k < NX; ++k) s += fb2[k] * fw1[(long)k * HID + j];
  biasDH[j] = s;
}

// DH[0][j] = f_b1[j] + u0 @ W1u[:,j] + x0 @ W1x[:,j]   (z_0)
__global__ void fixup_row0_kernel(const float* __restrict__ fw1, const float* __restrict__ fb1,
                                  const float* __restrict__ u, const float* __restrict__ x0,
                                  ushort* __restrict__ DH) {
  int j = blockIdx.x * blockDim.x + threadIdx.x;
  float s = fb1[j];
  for (int k = 0; k < NU; ++k) s += u[k] * fw1[(long)(NX + k) * HID + j];
  for (int k = 0; k < NX; ++k) s += x0[k] * fw1[(long)k * HID + j];
  DH[j] = f2bf(s);
}

__global__ void x0_row_kernel(const float* __restrict__ x0, ushort* __restrict__ X) {
  int j = blockIdx.x * blockDim.x + threadIdx.x;
  if (j < NX) X[j] = f2bf(x0[j]);
}

// ---------------- generic bf16 MFMA GEMM ----------------
// C[M,N] = act( A[M,K] @ B[K,N] + bias ),  B supplied transposed as BT[N,K].
// flags: 1 = tanh, 2 = fp32 output (else bf16)
#define GBM 128
#define GBN 128
#define GBK 32
#define LDT 40   // padded LDS stride (bf16 elems); 80B keeps 16B alignment, ~2-way banks

__global__ __launch_bounds__(256) void gemm_kernel(
    const ushort* __restrict__ A, const ushort* __restrict__ BT,
    void* __restrict__ Cout, const float* __restrict__ bias,
    int M, int N, int K, int flags)
{
  __shared__ ushort Al[GBM * LDT];
  __shared__ ushort Bl[GBN * LDT];
  const int tid = threadIdx.x;
  const int bm = blockIdx.y, bn = blockIdx.x;
  const int wave = tid >> 6, lane = tid & 63;
  const int wr = wave >> 1, wc = wave & 1;
  const int l15 = lane & 15, l4 = lane >> 4;

  f32x4 acc[4][4];
#pragma unroll
  for (int m = 0; m < 4; ++m)
#pragma unroll
    for (int n = 0; n < 4; ++n) acc[m][n] = (f32x4){0.f, 0.f, 0.f, 0.f};

  const int r_t = tid >> 1;
  const int h_t = (tid & 1) * 16;
  const long arow = (long)bm * GBM + r_t;
  const long brow = (long)bn * GBN + r_t;

  for (int k0 = 0; k0 < K; k0 += GBK) {
    uint4 a0 = make_uint4(0,0,0,0), a1 = make_uint4(0,0,0,0);
    if (arow < M) {
      const ushort* p = A + arow * K + k0 + h_t;
      a0 = *(const uint4*)p;
      a1 = *(const uint4*)(p + 8);
    }
    const ushort* q = BT + brow * K + k0 + h_t;
    uint4 b0 = *(const uint4*)q;
    uint4 b1 = *(const uint4*)(q + 8);
    __syncthreads();
    *(uint4*)&Al[r_t * LDT + h_t]     = a0;
    *(uint4*)&Al[r_t * LDT + h_t + 8] = a1;
    *(uint4*)&Bl[r_t * LDT + h_t]     = b0;
    *(uint4*)&Bl[r_t * LDT + h_t + 8] = b1;
    __syncthreads();

    bf16x8 af[4], bfv[4];
#pragma unroll
    for (int m = 0; m < 4; ++m)
      af[m] = *(const bf16x8*)&Al[(wr * 64 + m * 16 + l15) * LDT + l4 * 8];
#pragma unroll
    for (int n = 0; n < 4; ++n)
      bfv[n] = *(const bf16x8*)&Bl[(wc * 64 + n * 16 + l15) * LDT + l4 * 8];
#pragma unroll
    for (int m = 0; m < 4; ++m)
#pragma unroll
      for (int n = 0; n < 4; ++n)
        acc[m][n] = __builtin_amdgcn_mfma_f32_16x16x32_bf16(af[m], bfv[n], acc[m][n], 0, 0, 0);
  }

  const bool f32out = (flags & 2) != 0;
  const bool dotanh = (flags & 1) != 0;
#pragma unroll
  for (int m = 0; m < 4; ++m) {
#pragma unroll
    for (int n = 0; n < 4; ++n) {
#pragma unroll
      for (int j = 0; j < 4; ++j) {
        long grow = (long)bm * GBM + wr * 64 + m * 16 + l4 * 4 + j;
        int  gcol = bn * GBN + wc * 64 + n * 16 + l15;
        if (grow < M) {
          float v = acc[m][n][j];
          if (bias) v += bias[gcol];
          if (dotanh) v = tanhf(v);
          if (f32out) ((float*)Cout)[grow * N + gcol] = v;
          else        ((ushort*)Cout)[grow * N + gcol] = f2bf(v);
        }
      }
    }
  }
}

// ---------------- persistent sequential kernel ----------------
// z_{t+1} = h_t @ M + D[t+1];  h = tanh(z).  MT is M transposed: [4096 cols][4096 k], bf16.
// DH[t] holds D[t] (bf16) until step t overwrites each WG's own 16 columns with h_t.
__global__ __launch_bounds__(SEQ_BLK, 1) void seq_kernel(
    const ushort* __restrict__ MT, ushort* __restrict__ DH,
    unsigned int* cnt, int nsteps)
{
  extern __shared__ ushort smem[];
  ushort* Ml = smem;                       // [16][4096] bf16
  ushort* hl = smem + COLS_PER_WG * HID;   // [4096] bf16

  const int tid = threadIdx.x;
  const int w = blockIdx.x;

  // load M column-slice into LDS (16 rows of MT, 128 KB)
  {
    const uint4* src = (const uint4*)(MT + (long)w * COLS_PER_WG * HID);
    uint4* dst = (uint4*)Ml;
#pragma unroll
    for (int i = 0; i < 16; ++i)
      dst[tid + SEQ_BLK * i] = src[tid + SEQ_BLK * i];
  }
  // prologue: h_0 = tanh(z_0) on own columns (DH row 0 currently holds z_0)
  if (tid < COLS_PER_WG) {
    int gcol = w * COLS_PER_WG + tid;
    DH[gcol] = f2bf(tanhf(bf2f(DH[gcol])));
  }
  __syncthreads();
  if (tid == 0) {
    __threadfence();
    __hip_atomic_fetch_add(cnt, 1u, __ATOMIC_RELAXED, __HIP_MEMORY_SCOPE_AGENT);
  }

  const int col = tid >> 5;     // 16 columns per WG, 32 lanes each
  const int ksub = tid & 31;
  const ushort* Mrow = Ml + col * HID;

  for (int t = 0; t < nsteps; ++t) {
    if (tid == 0) {
      unsigned int target = (unsigned int)SEQ_WGS * (unsigned int)(t + 1);
      while (__hip_atomic_load(cnt, __ATOMIC_RELAXED, __HIP_MEMORY_SCOPE_AGENT) < target) {
        __builtin_amdgcn_s_sleep(1);
      }
      __threadfence();   // acquire: invalidate stale L1/L2 before h reads
    }
    __syncthreads();
    // stage h_t row (8 KB) into LDS
    {
      const uint4* hsrc = (const uint4*)(DH + (long)t * HID);
      ((uint4*)hl)[tid] = hsrc[tid];
    }
    __syncthreads();
    // dot: z_{t+1}[gcol] partial over k = ksub*8 + i*256 (+0..7)
    float acc = 0.f;
#pragma unroll 4
    for (int i = 0; i < 16; ++i) {
      int k = ksub * 8 + i * 256;
      uint4 mv = *(const uint4*)(Mrow + k);
      uint4 hv = *(const uint4*)(hl + k);
#pragma unroll
      for (int q = 0; q < 4; ++q) {
        uint32_t mu = ((const uint32_t*)&mv)[q];
        uint32_t hu = ((const uint32_t*)&hv)[q];
        union { uint32_t i; float f; } a0, a1, b0, b1;
        a0.i = mu << 16; a1.i = mu & 0xffff0000u;
        b0.i = hu << 16; b1.i = hu & 0xffff0000u;
        acc = fmaf(a0.f, b0.f, acc);
        acc = fmaf(a1.f, b1.f, acc);
      }
    }
#pragma unroll
    for (int off = 16; off >= 1; off >>= 1)
      acc += __shfl_xor(acc, off, 64);
    if (ksub == 0) {
      int gcol = w * COLS_PER_WG + col;
      long idx = (long)(t + 1) * HID + gcol;
      float z = acc + bf2f(DH[idx]);     // add D[t+1]
      DH[idx] = f2bf(tanhf(z));          // overwrite with h_{t+1}
    }
    __syncthreads();
    if (tid == 0) {
      __threadfence();   // release: push h stores to LLC
      __hip_atomic_fetch_add(cnt, 1u, __ATOMIC_RELAXED, __HIP_MEMORY_SCOPE_AGENT);
    }
  }
}

// ---------------- launch ----------------

extern "C" void kernel_launch(void* const* d_in, const int* in_sizes, int n_in,
                              void* d_out, int out_size, void* d_ws, size_t ws_size,
                              hipStream_t stream) {
  const float* x0  = (const float*)d_in[0];
  const float* u   = (const float*)d_in[1];
  const float* fw1 = (const float*)d_in[2];
  const float* fb1 = (const float*)d_in[3];
  const float* fw2 = (const float*)d_in[4];
  const float* fb2 = (const float*)d_in[5];
  const float* gw1 = (const float*)d_in[6];
  const float* gb1 = (const float*)d_in[7];
  const float* gw2 = (const float*)d_in[8];
  const float* gb2 = (const float*)d_in[9];
  float* out = (float*)d_out;

  char* ws = (char*)d_ws;
  size_t off = 0;
  auto alloc = [&](size_t bytes) -> char* {
    char* p = ws + off; off += (bytes + 255) & ~(size_t)255; return p;
  };
  ushort* MT     = (ushort*)alloc((size_t)HID * HID * 2);
  ushort* DH     = (ushort*)alloc((size_t)T_STEPS * HID * 2);
  ushort* X      = (ushort*)alloc((size_t)T_STEPS * NX * 2);
  ushort* W1xT   = (ushort*)alloc((size_t)HID * NX * 2);
  ushort* W1uT   = (ushort*)alloc((size_t)HID * NU * 2);
  ushort* W2bf   = (ushort*)alloc((size_t)HID * NX * 2);
  ushort* W2T    = (ushort*)alloc((size_t)NX * HID * 2);
  ushort* Gw1T   = (ushort*)alloc((size_t)HID * NX * 2);
  ushort* Gw2T   = (ushort*)alloc((size_t)NY * HID * 2);
  ushort* Ubf    = (ushort*)alloc((size_t)T_STEPS * NU * 2);
  float*  biasDH = (float*)alloc((size_t)HID * 4);
  unsigned int* cnt = (unsigned int*)alloc(256);
  if (off > ws_size) return;  // workspace too small; bail

  init_cnt_kernel<<<1, 64, 0, stream>>>(cnt);
  cvt_bf16_kernel<<<2048, 256, 0, stream>>>(u, Ubf, T_STEPS * NU);
  cvt_bf16_kernel<<<2048, 256, 0, stream>>>(fw2, W2bf, HID * NX);
  transpose_cvt_kernel<<<dim3(HID/32, NX/32), dim3(32, 8), 0, stream>>>(fw1, W1xT, NX, HID);
  transpose_cvt_kernel<<<dim3(HID/32, NU/32), dim3(32, 8), 0, stream>>>(fw1 + (size_t)NX * HID, W1uT, NU, HID);
  transpose_cvt_kernel<<<dim3(NX/32, HID/32), dim3(32, 8), 0, stream>>>(fw2, W2T, HID, NX);
  transpose_cvt_kernel<<<dim3(HID/32, NX/32), dim3(32, 8), 0, stream>>>(gw1, Gw1T, NX, HID);
  transpose_cvt_kernel<<<dim3(NY/32, HID/32), dim3(32, 8), 0, stream>>>(gw2, Gw2T, HID, NY);
  bias_dh_kernel<<<HID/256, 256, 0, stream>>>(fw1, fb1, fb2, biasDH);

  // MT[j][k] = M[k][j] = sum_p W2[k][p] * W1x[p][j]  -> A=W1xT [HID,NX], BT=W2bf [HID,NX]
  gemm_kernel<<<dim3(HID/128, HID/128), 256, 0, stream>>>(W1xT, W2bf, MT, nullptr, HID, HID, NX, 0);
  // DH = Ubf @ W1u + (b1 + b2@W1x)   -> A=Ubf [T,NU], BT=W1uT [HID,NU]
  gemm_kernel<<<dim3(HID/128, T_STEPS/128), 256, 0, stream>>>(Ubf, W1uT, DH, biasDH, T_STEPS, HID, NU, 0);
  fixup_row0_kernel<<<HID/256, 256, 0, stream>>>(fw1, fb1, u, x0, DH);

  // sequential recurrence: h_{t+1} = tanh(h_t @ M + D[t+1]), t = 0..8189
  {
    (void)hipFuncSetAttribute((const void*)seq_kernel,
                              hipFuncAttributeMaxDynamicSharedMemorySize, SEQ_LDS);
    int nsteps = T_STEPS - 2;  // produce h_1 .. h_8190
    void* MT_p = (void*)MT; void* DH_p = (void*)DH; void* cnt_p = (void*)cnt;
    void* args[] = { &MT_p, &DH_p, &cnt_p, &nsteps };
    hipError_t e = hipLaunchCooperativeKernel((const void*)seq_kernel, dim3(SEQ_WGS),
                                              dim3(SEQ_BLK), args, SEQ_LDS, stream);
    if (e != hipSuccess) {
      (void)hipGetLastError();
      seq_kernel<<<SEQ_WGS, SEQ_BLK, SEQ_LDS, stream>>>(MT, DH, cnt, nsteps);
    }
  }

  x0_row_kernel<<<NX/256, 256, 0, stream>>>(x0, X);
  // X[1..8191] = H[0..8190] @ W2 + b2  -> A=DH [8191,HID], BT=W2T [NX,HID]
  gemm_kernel<<<dim3(NX/128, T_STEPS/128), 256, 0, stream>>>(DH, W2T, X + NX, fb2, T_STEPS - 1, NX, HID, 0);
  // G = tanh(X @ g_w1 + g_b1) -> reuse DH buffer
  gemm_kernel<<<dim3(HID/128, T_STEPS/128), 256, 0, stream>>>(X, Gw1T, DH, gb1, T_STEPS, HID, NX, 1);
  // Y = G @ g_w2 + g_b2 -> fp32 out
  gemm_kernel<<<dim3(NY/128, T_STEPS/128), 256, 0, stream>>>(DH, Gw2T, out, gb2, T_STEPS, NY, HID, 2);
}

// Round 2
// 19660.056 us; speedup vs baseline: 8.2028x; 8.2028x over previous
//
#include <hip/hip_runtime.h>
#include <hip/hip_bf16.h>
#include <stdint.h>

#define T_STEPS 8192
#define NX 1024
#define NU 512
#define NY 128
#define HID 4096

#define SEQ_WGS 256
#define SEQ_BLK 512

typedef __attribute__((ext_vector_type(8))) short bf16x8;
typedef __attribute__((ext_vector_type(4))) float f32x4;

__device__ __forceinline__ float bf2f(ushort u) {
  union { uint32_t i; float f; } v; v.i = ((uint32_t)u) << 16; return v.f;
}
__device__ __forceinline__ ushort f2bf(float f) {
  union { float f; uint32_t i; } v; v.f = f;
  uint32_t r = v.i + 0x7fffu + ((v.i >> 16) & 1u);
  return (ushort)(r >> 16);
}
__device__ __forceinline__ float lof(uint32_t u) {
  union { uint32_t i; float f; } v; v.i = u << 16; return v.f;
}
__device__ __forceinline__ float hif(uint32_t u) {
  union { uint32_t i; float f; } v; v.i = u & 0xffff0000u; return v.f;
}

// ---------------- small utility kernels ----------------

__global__ void cvt_bf16_kernel(const float* __restrict__ in, ushort* __restrict__ out, int n) {
  int i = blockIdx.x * blockDim.x + threadIdx.x;
  int stride = gridDim.x * blockDim.x;
  for (; i < n; i += stride) out[i] = f2bf(in[i]);
}

// out[C][R] = (bf16) in[R][C]
__global__ void transpose_cvt_kernel(const float* __restrict__ in, ushort* __restrict__ out,
                                     int R, int C) {
  __shared__ float tile[32][33];
  int bx = blockIdx.x, by = blockIdx.y;
  int tx = threadIdx.x, ty = threadIdx.y;  // 32 x 8
#pragma unroll
  for (int yy = 0; yy < 4; ++yy) {
    long r = (long)by * 32 + ty + yy * 8;
    long c = (long)bx * 32 + tx;
    tile[ty + yy * 8][tx] = in[r * C + c];
  }
  __syncthreads();
#pragma unroll
  for (int yy = 0; yy < 4; ++yy) {
    long c = (long)bx * 32 + ty + yy * 8;  // out row
    long r = (long)by * 32 + tx;           // out col
    out[c * R + r] = f2bf(tile[tx][ty + yy * 8]);
  }
}

// biasDH[j] = f_b1[j] + sum_k f_b2[k] * f_w1[k][j]
__global__ void bias_dh_kernel(const float* __restrict__ fw1, const float* __restrict__ fb1,
                               const float* __restrict__ fb2, float* __restrict__ biasDH) {
  int j = blockIdx.x * blockDim.x + threadIdx.x;
  float s = fb1[j];
  for (int k = 0; k < NX; ++k) s += fb2[k] * fw1[(long)k * HID + j];
  biasDH[j] = s;
}

// z_0[j] = f_b1[j] + u0 @ W1u[:,j] + x0 @ W1x[:,j]; h_0 = tanh(z_0)
// Publish h_0: bf16 into DH row 0 (for recovery GEMM) and tagged word (tag 0) into slot 0.
__global__ void fixup_row0_kernel(const float* __restrict__ fw1, const float* __restrict__ fb1,
                                  const float* __restrict__ u, const float* __restrict__ x0,
                                  ushort* __restrict__ DH, uint32_t* __restrict__ htag) {
  int j = blockIdx.x * blockDim.x + threadIdx.x;
  float s = fb1[j];
  for (int k = 0; k < NU; ++k) s += u[k] * fw1[(long)(NX + k) * HID + j];
  for (int k = 0; k < NX; ++k) s += x0[k] * fw1[(long)k * HID + j];
  float h = tanhf(s);
  ushort hb = f2bf(h);
  DH[j] = hb;
  htag[j] = ((uint32_t)hb << 16);  // tag = 0
}

__global__ void x0_row_kernel(const float* __restrict__ x0, ushort* __restrict__ X) {
  int j = blockIdx.x * blockDim.x + threadIdx.x;
  if (j < NX) X[j] = f2bf(x0[j]);
}

// ---------------- generic bf16 MFMA GEMM ----------------
// C[M,N] = act( A[M,K] @ B[K,N] + bias ),  B supplied transposed as BT[N,K].
// flags: 1 = tanh, 2 = fp32 output (else bf16)
#define GBM 128
#define GBN 128
#define GBK 32
#define LDT 40

__global__ __launch_bounds__(256) void gemm_kernel(
    const ushort* __restrict__ A, const ushort* __restrict__ BT,
    void* __restrict__ Cout, const float* __restrict__ bias,
    int M, int N, int K, int flags)
{
  __shared__ ushort Al[GBM * LDT];
  __shared__ ushort Bl[GBN * LDT];
  const int tid = threadIdx.x;
  const int bm = blockIdx.y, bn = blockIdx.x;
  const int wave = tid >> 6, lane = tid & 63;
  const int wr = wave >> 1, wc = wave & 1;
  const int l15 = lane & 15, l4 = lane >> 4;

  f32x4 acc[4][4];
#pragma unroll
  for (int m = 0; m < 4; ++m)
#pragma unroll
    for (int n = 0; n < 4; ++n) acc[m][n] = (f32x4){0.f, 0.f, 0.f, 0.f};

  const int r_t = tid >> 1;
  const int h_t = (tid & 1) * 16;
  const long arow = (long)bm * GBM + r_t;
  const long brow = (long)bn * GBN + r_t;

  for (int k0 = 0; k0 < K; k0 += GBK) {
    uint4 a0 = make_uint4(0,0,0,0), a1 = make_uint4(0,0,0,0);
    if (arow < M) {
      const ushort* p = A + arow * K + k0 + h_t;
      a0 = *(const uint4*)p;
      a1 = *(const uint4*)(p + 8);
    }
    const ushort* q = BT + brow * K + k0 + h_t;
    uint4 b0 = *(const uint4*)q;
    uint4 b1 = *(const uint4*)(q + 8);
    __syncthreads();
    *(uint4*)&Al[r_t * LDT + h_t]     = a0;
    *(uint4*)&Al[r_t * LDT + h_t + 8] = a1;
    *(uint4*)&Bl[r_t * LDT + h_t]     = b0;
    *(uint4*)&Bl[r_t * LDT + h_t + 8] = b1;
    __syncthreads();

    bf16x8 af[4], bfv[4];
#pragma unroll
    for (int m = 0; m < 4; ++m)
      af[m] = *(const bf16x8*)&Al[(wr * 64 + m * 16 + l15) * LDT + l4 * 8];
#pragma unroll
    for (int n = 0; n < 4; ++n)
      bfv[n] = *(const bf16x8*)&Bl[(wc * 64 + n * 16 + l15) * LDT + l4 * 8];
#pragma unroll
    for (int m = 0; m < 4; ++m)
#pragma unroll
      for (int n = 0; n < 4; ++n)
        acc[m][n] = __builtin_amdgcn_mfma_f32_16x16x32_bf16(af[m], bfv[n], acc[m][n], 0, 0, 0);
  }

  const bool f32out = (flags & 2) != 0;
  const bool dotanh = (flags & 1) != 0;
#pragma unroll
  for (int m = 0; m < 4; ++m) {
#pragma unroll
    for (int n = 0; n < 4; ++n) {
#pragma unroll
      for (int j = 0; j < 4; ++j) {
        long grow = (long)bm * GBM + wr * 64 + m * 16 + l4 * 4 + j;
        int  gcol = bn * GBN + wc * 64 + n * 16 + l15;
        if (grow < M) {
          float v = acc[m][n][j];
          if (bias) v += bias[gcol];
          if (dotanh) v = tanhf(v);
          if (f32out) ((float*)Cout)[grow * N + gcol] = v;
          else        ((ushort*)Cout)[grow * N + gcol] = f2bf(v);
        }
      }
    }
  }
}

// ---------------- persistent sequential kernel (dataflow-synced) ----------------
// h_{i+1} = tanh(h_i @ M + D[i+1]).
// Publication: each h element is one u32 word: (bf16(h) << 16) | (step & 0xffff),
// stored with relaxed AGENT-scope atomics (bypass non-coherent L2, land in MALL).
// Readers poll the words themselves — no barrier, no fences, no RMW contention.
// Ping-pong depth 2 over htag[2][HID]; safe: producing h_{i+2} requires every WG
// consumed h_i (overwrite target) already.
// M is register-resident: each thread holds 128 f32 values (its (col, k-slice)).
__global__ __launch_bounds__(SEQ_BLK, 2) void seq_kernel(
    const ushort* __restrict__ MT, ushort* __restrict__ DH,
    uint32_t* __restrict__ htag, int nsteps)
{
  __shared__ ushort hl[HID];
  const int tid = threadIdx.x;
  const int w = blockIdx.x;
  const int col = tid >> 5;     // 16 cols per WG, 32 lanes each
  const int ksub = tid & 31;
  const int gcol = (w << 4) + col;

  // Load this thread's M values: MT[gcol][k] for k in {ksub*8 + 256*j + 0..7}
  float4 mreg[32];
  {
    const uint4* mrow = (const uint4*)(MT + (size_t)gcol * HID);
#pragma unroll
    for (int j = 0; j < 16; ++j) {
      uint4 m = mrow[ksub + 32 * j];
      mreg[2 * j]     = make_float4(lof(m.x), hif(m.x), lof(m.y), hif(m.y));
      mreg[2 * j + 1] = make_float4(lof(m.z), hif(m.z), lof(m.w), hif(m.w));
    }
  }

  const bool prod = (ksub == 0);

  for (int i = 0; i < nsteps; ++i) {
    // Prefetch D_{i+1}[gcol] (own column; written only by pre-GEMM, safe anytime).
    float dnext = 0.f;
    if (prod) dnext = bf2f(DH[(size_t)(i + 1) * HID + gcol]);

    // ---- poll + stage h_i (thread owns words tid + 512*j) ----
    {
      uint32_t* slot = htag + (size_t)(i & 1) * HID;
      const uint32_t target = (uint32_t)i & 0xffffu;
      uint32_t x[8];
      bool pend[8];
#pragma unroll
      for (int j = 0; j < 8; ++j) pend[j] = true;
      int rem = 8;
      while (rem) {
#pragma unroll
        for (int j = 0; j < 8; ++j)
          if (pend[j])
            x[j] = __hip_atomic_load(&slot[tid + 512 * j], __ATOMIC_RELAXED,
                                     __HIP_MEMORY_SCOPE_AGENT);
#pragma unroll
        for (int j = 0; j < 8; ++j)
          if (pend[j] && (x[j] & 0xffffu) == target) { pend[j] = false; --rem; }
        if (rem) __builtin_amdgcn_s_sleep(1);
      }
#pragma unroll
      for (int j = 0; j < 8; ++j) hl[tid + 512 * j] = (ushort)(x[j] >> 16);
    }
    __syncthreads();

    // ---- dot: z_{i+1}[gcol] partial over this lane's k-slice ----
    float a0 = 0.f, a1 = 0.f, a2 = 0.f, a3 = 0.f;
    const ushort* hp = hl + ksub * 8;
#pragma unroll
    for (int j = 0; j < 16; ++j) {
      uint4 hv = *(const uint4*)(hp + 256 * j);
      float4 m0 = mreg[2 * j], m1 = mreg[2 * j + 1];
      a0 = fmaf(m0.x, lof(hv.x), a0);
      a1 = fmaf(m0.y, hif(hv.x), a1);
      a2 = fmaf(m0.z, lof(hv.y), a2);
      a3 = fmaf(m0.w, hif(hv.y), a3);
      a0 = fmaf(m1.x, lof(hv.z), a0);
      a1 = fmaf(m1.y, hif(hv.z), a1);
      a2 = fmaf(m1.z, lof(hv.w), a2);
      a3 = fmaf(m1.w, hif(hv.w), a3);
    }
    float acc = (a0 + a1) + (a2 + a3);
#pragma unroll
    for (int off = 16; off >= 1; off >>= 1)
      acc += __shfl_xor(acc, off, 64);

    if (prod) {
      float h = tanhf(acc + dnext);
      ushort hb = f2bf(h);
      uint32_t word = ((uint32_t)hb << 16) | ((uint32_t)(i + 1) & 0xffffu);
      __hip_atomic_store(htag + (size_t)((i + 1) & 1) * HID + gcol, word,
                         __ATOMIC_RELAXED, __HIP_MEMORY_SCOPE_AGENT);
      DH[(size_t)(i + 1) * HID + gcol] = hb;   // for recovery GEMM (cached is fine)
    }
    __syncthreads();  // hl reused next iteration
  }
}

// ---------------- launch ----------------

extern "C" void kernel_launch(void* const* d_in, const int* in_sizes, int n_in,
                              void* d_out, int out_size, void* d_ws, size_t ws_size,
                              hipStream_t stream) {
  const float* x0  = (const float*)d_in[0];
  const float* u   = (const float*)d_in[1];
  const float* fw1 = (const float*)d_in[2];
  const float* fb1 = (const float*)d_in[3];
  const float* fw2 = (const float*)d_in[4];
  const float* fb2 = (const float*)d_in[5];
  const float* gw1 = (const float*)d_in[6];
  const float* gb1 = (const float*)d_in[7];
  const float* gw2 = (const float*)d_in[8];
  const float* gb2 = (const float*)d_in[9];
  float* out = (float*)d_out;

  char* ws = (char*)d_ws;
  size_t off = 0;
  auto alloc = [&](size_t bytes) -> char* {
    char* p = ws + off; off += (bytes + 255) & ~(size_t)255; return p;
  };
  ushort* MT     = (ushort*)alloc((size_t)HID * HID * 2);
  ushort* DH     = (ushort*)alloc((size_t)T_STEPS * HID * 2);
  ushort* X      = (ushort*)alloc((size_t)T_STEPS * NX * 2);
  ushort* W1xT   = (ushort*)alloc((size_t)HID * NX * 2);
  ushort* W1uT   = (ushort*)alloc((size_t)HID * NU * 2);
  ushort* W2bf   = (ushort*)alloc((size_t)HID * NX * 2);
  ushort* W2T    = (ushort*)alloc((size_t)NX * HID * 2);
  ushort* Gw1T   = (ushort*)alloc((size_t)HID * NX * 2);
  ushort* Gw2T   = (ushort*)alloc((size_t)NY * HID * 2);
  ushort* Ubf    = (ushort*)alloc((size_t)T_STEPS * NU * 2);
  float*  biasDH = (float*)alloc((size_t)HID * 4);
  uint32_t* htag = (uint32_t*)alloc((size_t)2 * HID * 4);
  if (off > ws_size) return;  // workspace too small; bail

  cvt_bf16_kernel<<<2048, 256, 0, stream>>>(u, Ubf, T_STEPS * NU);
  cvt_bf16_kernel<<<2048, 256, 0, stream>>>(fw2, W2bf, HID * NX);
  transpose_cvt_kernel<<<dim3(HID/32, NX/32), dim3(32, 8), 0, stream>>>(fw1, W1xT, NX, HID);
  transpose_cvt_kernel<<<dim3(HID/32, NU/32), dim3(32, 8), 0, stream>>>(fw1 + (size_t)NX * HID, W1uT, NU, HID);
  transpose_cvt_kernel<<<dim3(NX/32, HID/32), dim3(32, 8), 0, stream>>>(fw2, W2T, HID, NX);
  transpose_cvt_kernel<<<dim3(HID/32, NX/32), dim3(32, 8), 0, stream>>>(gw1, Gw1T, NX, HID);
  transpose_cvt_kernel<<<dim3(NY/32, HID/32), dim3(32, 8), 0, stream>>>(gw2, Gw2T, HID, NY);
  bias_dh_kernel<<<HID/256, 256, 0, stream>>>(fw1, fb1, fb2, biasDH);

  // MT[j][k] = M[k][j] = sum_p W2[k][p] * W1x[p][j]
  gemm_kernel<<<dim3(HID/128, HID/128), 256, 0, stream>>>(W1xT, W2bf, MT, nullptr, HID, HID, NX, 0);
  // DH = Ubf @ W1u + (b1 + b2@W1x)
  gemm_kernel<<<dim3(HID/128, T_STEPS/128), 256, 0, stream>>>(Ubf, W1uT, DH, biasDH, T_STEPS, HID, NU, 0);
  // h_0 into DH row 0 + tagged slot 0
  fixup_row0_kernel<<<HID/256, 256, 0, stream>>>(fw1, fb1, u, x0, DH, htag);

  // sequential recurrence: h_{i+1} = tanh(h_i @ M + D[i+1]), i = 0..8189
  {
    int nsteps = T_STEPS - 2;  // produce h_1 .. h_8190
    void* MT_p = (void*)MT; void* DH_p = (void*)DH; void* ht_p = (void*)htag;
    void* args[] = { &MT_p, &DH_p, &ht_p, &nsteps };
    hipError_t e = hipLaunchCooperativeKernel((const void*)seq_kernel, dim3(SEQ_WGS),
                                              dim3(SEQ_BLK), args, 0, stream);
    if (e != hipSuccess) {
      (void)hipGetLastError();
      seq_kernel<<<SEQ_WGS, SEQ_BLK, 0, stream>>>(MT, DH, htag, nsteps);
    }
  }

  x0_row_kernel<<<NX/256, 256, 0, stream>>>(x0, X);
  // X[1..8191] = H[0..8190] @ W2 + b2
  gemm_kernel<<<dim3(NX/128, T_STEPS/128), 256, 0, stream>>>(DH, W2T, X + NX, fb2, T_STEPS - 1, NX, HID, 0);
  // G = tanh(X @ g_w1 + g_b1) -> reuse DH buffer
  gemm_kernel<<<dim3(HID/128, T_STEPS/128), 256, 0, stream>>>(X, Gw1T, DH, gb1, T_STEPS, HID, NX, 1);
  // Y = G @ g_w2 + g_b2 -> fp32 out
  gemm_kernel<<<dim3(NY/128, T_STEPS/128), 256, 0, stream>>>(DH, Gw2T, out, gb2, T_STEPS, NY, HID, 2);
}